// Round 15
// baseline (184.000 us; speedup 1.0000x reference)
//
#include <hip/hip_runtime.h>
#include <hip/hip_bf16.h>

typedef __attribute__((ext_vector_type(8))) short short8;
typedef __attribute__((ext_vector_type(4))) short short4v;
typedef __attribute__((ext_vector_type(4))) float f32x4;

#define MFMA(A,B,C) __builtin_amdgcn_mfma_f32_16x16x32_bf16(A,B,C,0,0,0)
// swizzle for BK=64 tiles (bits {0,1,3} of row)
#define SW(row) ((((row) & 3)) | (((row) >> 1) & 4))
// swizzle for BK=32 tiles (colgroup ^= f(row)): even bank spread, 2-way max (free)
#define SW32(row) ((((row) & 3)) ^ (((row) >> 2) & 3))
#define SCL 0.18033688f  // 0.125 * log2(e): folded into Q so scores are base-2

__device__ __forceinline__ short f2bs(float f) {
    __hip_bfloat16 h = __float2bfloat16(f);
    union { __hip_bfloat16 h; short s; } u; u.h = h; return u.s;
}

__device__ __forceinline__ float exp2v(float x) {  // bare v_exp_f32 (D = 2^S0)
    float r; asm("v_exp_f32 %0, %1" : "=v"(r) : "v"(x)); return r;
}

__device__ __forceinline__ unsigned cvtpk(float a, float b) {  // bf16(a) | bf16(b)<<16
    unsigned r; asm("v_cvt_pk_bf16_f32 %0, %1, %2" : "=v"(r) : "v"(a), "v"(b)); return r;
}

__device__ __forceinline__ void async16(void* lds, const void* g) {
    __builtin_amdgcn_global_load_lds(
        (const __attribute__((address_space(1))) unsigned int*)g,
        (__attribute__((address_space(3))) unsigned int*)lds, 16, 0, 0);
}

// ---------------- cast fp32 -> bf16, vectorized x4 ----------------
__global__ __launch_bounds__(256) void cast_bf16_k(const float* __restrict__ X,
                                                   short* __restrict__ Y, int n4) {
    int i = blockIdx.x * 256 + threadIdx.x;
    if (i >= n4) return;
    const float4 v = *(const float4*)(X + (size_t)i * 4);
    short4v o;
    o.x = f2bs(v.x); o.y = f2bs(v.y); o.z = f2bs(v.z); o.w = f2bs(v.w);
    *(short4v*)(Y + (size_t)i * 4) = o;
}

// ---------------- transpose + cast: Wt[n][k] = W[k][n] ----------------
__global__ __launch_bounds__(256) void transpose_cast_k(const float* __restrict__ W,
                                                        short* __restrict__ Wt, int K, int N) {
    __shared__ float tile[32][33];
    int n0 = blockIdx.x * 32, k0 = blockIdx.y * 32;
    int tx = threadIdx.x, ty = threadIdx.y;
    #pragma unroll
    for (int i = 0; i < 32; i += 8)
        tile[ty + i][tx] = W[(size_t)(k0 + ty + i) * N + n0 + tx];
    __syncthreads();
    #pragma unroll
    for (int i = 0; i < 32; i += 8)
        Wt[(size_t)(n0 + ty + i) * K + k0 + tx] = f2bs(tile[tx][ty + i]);
}

// ---------------- QKV GEMM: 256x256 tile, BK=32, ring-of-3 (96 KB) ----------------
// 8 waves (2Mx4N), wave 128x64, 32 MFMA + 12 ds_read per K-tile, 64 K-tiles.
// 4 stage units/K-tile (A lo/hi, B lo/hi; each 128 rows x 64B) at distance 2;
// vmcnt(4) at tile end -> kt+1 landed, kt+2 in flight (never a hot drain).
// Epilogue: cols [0,2048) Q rope*SCL pack; [2048,2560) K rope pack;
//           [2560,3072) V transposed pack (b,8,64,2048).
__global__ __launch_bounds__(512, 2) void gemm_qkv_k(
    const short* __restrict__ A, const short* __restrict__ Bt,
    short* __restrict__ Cq, short* __restrict__ Ck, short* __restrict__ Cv,
    const float* __restrict__ rc, const float* __restrict__ rs,
    int M, int N, int K)
{
    extern __shared__ short lds[];   // 3 bufs x (A 256x32 | B 256x32) = 3 x 16384 shorts
    const int t = threadIdx.x;       // 512
    const int l = t & 63, w = t >> 6;    // 8 waves
    const int lo = l & 15, hi = l >> 4;
    const int wm = w >> 2, wn = w & 3;   // 2M x 4N

    const int nbx = gridDim.x;           // 16
    const int nwg = nbx * gridDim.y;     // 192
    const int bid0 = blockIdx.y * nbx + blockIdx.x;
    const int wg = (bid0 & 7) * (nwg >> 3) + (bid0 >> 3);
    const int tm = (wg % nbx) * 256, tn = (wg / nbx) * 256;

    const f32x4 z4 = {0.f, 0.f, 0.f, 0.f};
    f32x4 acc[8][4];
    #pragma unroll
    for (int m = 0; m < 8; ++m)
        #pragma unroll
        for (int n = 0; n < 4; ++n) acc[m][n] = z4;

    const int srow = t >> 2;                  // 0..127 (row within a 128-row unit)
    const int scol = (t & 3) ^ SW32(srow);    // SW32 ignores bit 7, unit-safe

    // unit u: 0/1 = A rows 0-127/128-255; 2/3 = B rows 0-127/128-255
    auto stage_unit = [&](int kt, int buf, int u) {
        short* dst = lds + buf * 16384 + u * 4096 + w * 512;  // wave-uniform dest
        const int row = (u & 1) * 128 + srow;
        const short* src = (u < 2)
            ? A  + (size_t)(tm + row) * K + kt * 32 + scol * 8
            : Bt + (size_t)(tn + row) * K + kt * 32 + scol * 8;
        async16(dst, src);
    };

    const int nkt = K >> 5;   // 64
    #pragma unroll
    for (int u = 0; u < 4; ++u) stage_unit(0, 0, u);
    #pragma unroll
    for (int u = 0; u < 4; ++u) stage_unit(1, 1, u);
    asm volatile("s_waitcnt vmcnt(4)" ::: "memory");   // tile 0 landed
    __builtin_amdgcn_s_barrier();

    int cur = 0;
    for (int kt = 0; kt < nkt; ++kt) {
        int tgt = cur + 2; if (tgt >= 3) tgt -= 3;     // slot of tile kt-1, free
        const bool pf2 = (kt + 2 < nkt);
        const bool pf1 = (kt + 1 < nkt);
        const short* Ab_ = lds + cur * 16384;
        const short* Bb_ = Ab_ + 8192;
        short8 af[8], bfr[4];
        #pragma unroll
        for (int mm = 0; mm < 8; ++mm) {
            int row = wm * 128 + mm * 16 + lo;
            af[mm] = *(const short8*)(Ab_ + row * 32 + ((hi ^ SW32(row)) << 3));
        }
        #pragma unroll
        for (int n = 0; n < 4; ++n) {
            int row = wn * 64 + n * 16 + lo;
            bfr[n] = *(const short8*)(Bb_ + row * 32 + ((hi ^ SW32(row)) << 3));
        }
        if (pf2) {
            #pragma unroll
            for (int u = 0; u < 4; ++u) stage_unit(kt + 2, tgt, u);
        }
        __builtin_amdgcn_s_barrier();
        asm volatile("s_waitcnt lgkmcnt(0)" ::: "memory");
        __builtin_amdgcn_sched_barrier(0);
        __builtin_amdgcn_s_setprio(1);
        #pragma unroll
        for (int n = 0; n < 4; ++n)
            #pragma unroll
            for (int mm = 0; mm < 8; ++mm)
                acc[mm][n] = MFMA(af[mm], bfr[n], acc[mm][n]);
        __builtin_amdgcn_s_setprio(0);
        if (pf2)      asm volatile("s_waitcnt vmcnt(4)" ::: "memory");  // kt+1 landed
        else if (pf1) asm volatile("s_waitcnt vmcnt(0)" ::: "memory");
        __builtin_amdgcn_s_barrier();
        cur = (cur == 2) ? 0 : cur + 1;
    }

    const int ctn = tn + wn * 64;  // 64-col strip; stays within one region
    if (ctn < 2048) {              // ---- Q: rope + fold softmax scale ----
        #pragma unroll
        for (int m = 0; m < 8; ++m)
            #pragma unroll
            for (int r = 0; r < 4; ++r) {
                int row = tm + wm * 128 + m * 16 + hi * 4 + r;
                int b = row >> 11, s = row & 2047;
                #pragma unroll
                for (int n = 0; n < 2; ++n) {
                    int col = ctn + n * 16 + lo;
                    int h = col >> 6, d = col & 63;  // d < 32
                    float x1 = acc[m][n][r], x2 = acc[m][n + 2][r];
                    float c = rc[s * 32 + d], sn = rs[s * 32 + d];
                    size_t base = (((size_t)b * 32 + h) * 2048 + s) * 64;
                    Cq[base + d]      = f2bs((x1 * c - x2 * sn) * SCL);
                    Cq[base + d + 32] = f2bs((x1 * sn + x2 * c) * SCL);
                }
            }
    } else if (ctn < 2560) {       // ---- K: rope pack ----
        #pragma unroll
        for (int m = 0; m < 8; ++m)
            #pragma unroll
            for (int r = 0; r < 4; ++r) {
                int row = tm + wm * 128 + m * 16 + hi * 4 + r;
                int b = row >> 11, s = row & 2047;
                #pragma unroll
                for (int n = 0; n < 2; ++n) {
                    int col = ctn - 2048 + n * 16 + lo;
                    int h = col >> 6, d = col & 63;  // d < 32
                    float x1 = acc[m][n][r], x2 = acc[m][n + 2][r];
                    float c = rc[s * 32 + d], sn = rs[s * 32 + d];
                    size_t base = (((size_t)b * 8 + h) * 2048 + s) * 64;
                    Ck[base + d]      = f2bs(x1 * c - x2 * sn);
                    Ck[base + d + 32] = f2bs(x1 * sn + x2 * c);
                }
            }
    } else {                       // ---- V: transposed pack (b,8,64,2048) ----
        #pragma unroll
        for (int m = 0; m < 8; ++m)
            #pragma unroll
            for (int r = 0; r < 4; ++r) {
                int row = tm + wm * 128 + m * 16 + hi * 4 + r;
                int b = row >> 11, s = row & 2047;
                #pragma unroll
                for (int n = 0; n < 4; ++n) {
                    int col = ctn - 2560 + n * 16 + lo;
                    int h = col >> 6, d = col & 63;
                    Cv[(((size_t)b * 8 + h) * 64 + d) * 2048 + s] = f2bs(acc[m][n][r]);
                }
            }
    }
}

// ---------------- O-proj GEMM: 128x256 tile, BK=64, ring-of-3, counted vmcnt ----------------
__global__ __launch_bounds__(512, 2) void gemm_o_k(
    const short* __restrict__ A, const short* __restrict__ Bt,
    float* __restrict__ Cf, int M, int N, int K)
{
    extern __shared__ short lds[];   // 3 bufs x (A 128x64 | B 256x64) = 3 x 24576 shorts
    const int t = threadIdx.x;
    const int l = t & 63, w = t >> 6;
    const int lo = l & 15, hi = l >> 4;
    const int wm = w >> 2, wn = w & 3;     // 2M x 4N
    const int lr = l >> 3, ls = l & 7;

    const int nbx = gridDim.x;             // 32
    const int nwg = nbx * gridDim.y;       // 256
    const int bid0 = blockIdx.y * nbx + blockIdx.x;
    const int wg = (bid0 & 7) * (nwg >> 3) + (bid0 >> 3);
    const int tm = (wg % nbx) * 128, tn = (wg / nbx) * 256;

    const f32x4 z4 = {0.f, 0.f, 0.f, 0.f};
    f32x4 acc[4][4];
    #pragma unroll
    for (int m = 0; m < 4; ++m)
        #pragma unroll
        for (int n = 0; n < 4; ++n) acc[m][n] = z4;

    const int srow = w * 8 + lr;
    const int sswz = ls ^ SW(srow);

    auto stage_unit = [&](int kt, int buf, int u) {
        const size_t ko = (size_t)kt * 64;
        short* base = lds + buf * 24576;
        if (u < 2)
            async16(base + u * 4096 + w * 512,
                    A + (size_t)(tm + u * 64 + srow) * K + ko + sswz * 8);
        else
            async16(base + 8192 + (u - 2) * 4096 + w * 512,
                    Bt + (size_t)(tn + (u - 2) * 64 + srow) * K + ko + sswz * 8);
    };

    const int nkt = K >> 6;   // 32
    #pragma unroll
    for (int u = 0; u < 6; ++u) stage_unit(0, 0, u);
    #pragma unroll
    for (int u = 0; u < 6; ++u) stage_unit(1, 1, u);
    asm volatile("s_waitcnt vmcnt(6)" ::: "memory");
    __builtin_amdgcn_s_barrier();

    int cur = 0;
    for (int kt = 0; kt < nkt; ++kt) {
        int tgt = cur + 2; if (tgt >= 3) tgt -= 3;
        const bool pf2 = (kt + 2 < nkt);
        const bool pf1 = (kt + 1 < nkt);
        const short* Ab_ = lds + cur * 24576;
        const short* Bb_ = Ab_ + 8192;
        short8 af[4], bfr[4];
        #pragma unroll
        for (int ph = 0; ph < 2; ++ph) {
            const int slot = ph * 4 + hi;
            #pragma unroll
            for (int mm = 0; mm < 4; ++mm) {
                int row = wm * 64 + mm * 16 + lo;
                af[mm] = *(const short8*)(Ab_ + row * 64 + ((slot ^ SW(row)) << 3));
            }
            #pragma unroll
            for (int n = 0; n < 4; ++n) {
                int row = wn * 64 + n * 16 + lo;
                bfr[n] = *(const short8*)(Bb_ + row * 64 + ((slot ^ SW(row)) << 3));
            }
            if (pf2) {
                stage_unit(kt + 2, tgt, ph * 3);
                stage_unit(kt + 2, tgt, ph * 3 + 1);
                stage_unit(kt + 2, tgt, ph * 3 + 2);
            }
            __builtin_amdgcn_s_barrier();
            asm volatile("s_waitcnt lgkmcnt(0)" ::: "memory");
            __builtin_amdgcn_sched_barrier(0);
            __builtin_amdgcn_s_setprio(1);
            #pragma unroll
            for (int n = 0; n < 4; ++n)
                #pragma unroll
                for (int mm = 0; mm < 4; ++mm)
                    acc[mm][n] = MFMA(af[mm], bfr[n], acc[mm][n]);
            __builtin_amdgcn_s_setprio(0);
            if (ph == 1) {
                if (pf2)      asm volatile("s_waitcnt vmcnt(6)" ::: "memory");
                else if (pf1) asm volatile("s_waitcnt vmcnt(0)" ::: "memory");
            }
            __builtin_amdgcn_s_barrier();
        }
        cur = (cur == 2) ? 0 : cur + 1;
    }

    #pragma unroll
    for (int m = 0; m < 4; ++m)
        #pragma unroll
        for (int r = 0; r < 4; ++r) {
            int row = tm + wm * 64 + m * 16 + hi * 4 + r;
            #pragma unroll
            for (int n = 0; n < 4; ++n) {
                int col = tn + wn * 64 + n * 16 + lo;
                Cf[(size_t)row * N + col] = acc[m][n][r];
            }
        }
}

// ---------------- flash attention, pair-balanced, no-max softmax ----------------
__global__ __launch_bounds__(256) void attn_k(
    const short* __restrict__ Qp, const short* __restrict__ Kp, const short* __restrict__ Vt,
    short* __restrict__ Ab)
{
    __shared__ short KV[2][8192];  // [buf][ K:0..4095 | V:4096..8191 ], 32 KB
    const int t = threadIdx.x, l = t & 63, w = t >> 6;
    const int lo = l & 15, hi = l >> 4;
    const int lr = l >> 3, ls = l & 7;
    const int pair = blockIdx.x;   // 0..15
    const int h = blockIdx.y, b = blockIdx.z;
    const int kvh = h >> 2;
    const size_t qbase  = (size_t)(b * 32 + h) * 2048 * 64;
    const size_t kbase  = (size_t)(b * 8 + kvh) * 2048 * 64;
    const size_t vtbase = (size_t)(b * 8 + kvh) * 64 * 2048;
    const size_t abase  = (size_t)b * 2048 * 2048 + (size_t)h * 64;

    for (int halfq = 0; halfq < 2; ++halfq) {
        const int qtile = halfq ? 31 - pair : pair;
        const int nkt = qtile + 1;

        short8 qf[2];
        {
            int qrow = qtile * 64 + w * 16 + lo;
            #pragma unroll
            for (int ks = 0; ks < 2; ++ks)
                qf[ks] = *(const short8*)(Qp + qbase + (size_t)qrow * 64 + (ks * 4 + hi) * 8);
        }

        const f32x4 z4 = {0.f, 0.f, 0.f, 0.f};
        float l_run = 0.f;
        f32x4 oacc[4];
        #pragma unroll
        for (int nd = 0; nd < 4; ++nd) oacc[nd] = z4;

        #pragma unroll
        for (int j = 0; j < 2; ++j) {
            int g8 = w * 2 + j;
            int row = g8 * 8 + lr;
            int gs = ls ^ SW(row);
            async16(&KV[0][g8 * 512],        Kp + kbase + (size_t)row * 64 + gs * 8);
            async16(&KV[0][4096 + g8 * 512], Vt + vtbase + (size_t)row * 2048 + gs * 8);
        }
        __syncthreads();

        int cur = 0;
        for (int kt = 0; kt < nkt; ++kt) {
            if (kt + 1 < nkt) {
                #pragma unroll
                for (int j = 0; j < 2; ++j) {
                    int g8 = w * 2 + j;
                    int row = g8 * 8 + lr;
                    int gs = ls ^ SW(row);
                    async16(&KV[cur ^ 1][g8 * 512],
                            Kp + kbase + (size_t)((kt + 1) * 64 + row) * 64 + gs * 8);
                    async16(&KV[cur ^ 1][4096 + g8 * 512],
                            Vt + vtbase + (size_t)row * 2048 + (kt + 1) * 64 + gs * 8);
                }
            }

            const short* Ks = &KV[cur][0];
            const short* Vs = &KV[cur][4096];

            f32x4 sacc[4];
            #pragma unroll
            for (int n = 0; n < 4; ++n) sacc[n] = z4;
            __builtin_amdgcn_s_setprio(1);
            #pragma unroll
            for (int ks = 0; ks < 2; ++ks) {
                const int slot = ks * 4 + hi;
                #pragma unroll
                for (int n = 0; n < 4; ++n) {
                    const int krow = ((lo >> 2) << 3) + ((n & 1) << 2) + (lo & 3) + ((n >> 1) << 5);
                    short8 kf = *(const short8*)(Ks + krow * 64 + ((slot ^ SW(krow)) << 3));
                    sacc[n] = MFMA(kf, qf[ks], sacc[n]);
                }
            }
            __builtin_amdgcn_s_setprio(0);

            float p[4][4];
            if (kt == qtile) {
                const int q = qtile * 64 + w * 16 + lo;
                #pragma unroll
                for (int n = 0; n < 4; ++n)
                    #pragma unroll
                    for (int r = 0; r < 4; ++r) {
                        int k = kt * 64 + hi * 8 + ((n & 1) << 2) + r + ((n >> 1) << 5);
                        p[n][r] = exp2v((k > q) ? -3e38f : sacc[n][r]);
                    }
            } else {
                #pragma unroll
                for (int n = 0; n < 4; ++n)
                    #pragma unroll
                    for (int r = 0; r < 4; ++r)
                        p[n][r] = exp2v(sacc[n][r]);
            }
            float rs0 = 0.f, rs1 = 0.f;
            #pragma unroll
            for (int n = 0; n < 4; ++n) {
                rs0 += p[n][0] + p[n][1];
                rs1 += p[n][2] + p[n][3];
            }
            l_run += rs0 + rs1;

            short8 afr[2];
            #pragma unroll
            for (int ks = 0; ks < 2; ++ks) {
                union { short8 s; unsigned u[4]; } pk;
                pk.u[0] = cvtpk(p[2 * ks][0],     p[2 * ks][1]);
                pk.u[1] = cvtpk(p[2 * ks][2],     p[2 * ks][3]);
                pk.u[2] = cvtpk(p[2 * ks + 1][0], p[2 * ks + 1][1]);
                pk.u[3] = cvtpk(p[2 * ks + 1][2], p[2 * ks + 1][3]);
                afr[ks] = pk.s;
            }

            __builtin_amdgcn_s_setprio(1);
            #pragma unroll
            for (int ks = 0; ks < 2; ++ks) {
                const int slot = ks * 4 + hi;
                #pragma unroll
                for (int nd = 0; nd < 4; ++nd) {
                    const int vrow = nd * 16 + lo;
                    short8 vf = *(const short8*)(Vs + vrow * 64 + ((slot ^ SW(vrow)) << 3));
                    oacc[nd] = MFMA(afr[ks], vf, oacc[nd]);
                }
            }
            __builtin_amdgcn_s_setprio(0);

            __syncthreads();
            cur ^= 1;
        }

        l_run += __shfl_xor(l_run, 16, 64);
        l_run += __shfl_xor(l_run, 32, 64);
        float rl[4];
        #pragma unroll
        for (int r = 0; r < 4; ++r)
            rl[r] = 1.0f / __shfl(l_run, (l & 48) | (hi * 4 + r), 64);
        #pragma unroll
        for (int nd = 0; nd < 4; ++nd)
            #pragma unroll
            for (int r = 0; r < 4; ++r) {
                int s = qtile * 64 + w * 16 + hi * 4 + r;
                Ab[abase + (size_t)s * 2048 + nd * 16 + lo] = f2bs(oacc[nd][r] * rl[r]);
            }
    }
}

extern "C" void kernel_launch(void* const* d_in, const int* in_sizes, int n_in,
                              void* d_out, int out_size, void* d_ws, size_t ws_size,
                              hipStream_t stream)
{
    const float* x  = (const float*)d_in[0];
    const float* Wq = (const float*)d_in[1];
    const float* Wk = (const float*)d_in[2];
    const float* Wv = (const float*)d_in[3];
    const float* Wo = (const float*)d_in[4];
    const float* rc = (const float*)d_in[5];
    const float* rs = (const float*)d_in[6];
    float* out = (float*)d_out;
    char* ws = (char*)d_ws;

    size_t off = 0;
    short* x_bf   = (short*)(ws + off); off += (size_t)4096 * 2048 * 2;
    short* Wqkv_t = (short*)(ws + off); off += (size_t)3072 * 2048 * 2;
    short* Wo_t   = (short*)(ws + off); off += (size_t)2048 * 2048 * 2;
    short* Qp     = (short*)(ws + off); off += (size_t)2 * 32 * 2048 * 64 * 2;
    short* Kp     = (short*)(ws + off); off += (size_t)2 * 8 * 2048 * 64 * 2;
    short* Vtb    = (short*)(ws + off); off += (size_t)2 * 8 * 64 * 2048 * 2;
    short* Ab     = (short*)(ws + off); off += (size_t)4096 * 2048 * 2;
    if (off > ws_size) return;

    const int LDS_QKV = 3 * 16384 * 2;   // 96 KB ring-of-3
    const int LDS_O   = 3 * 24576 * 2;   // 144 KB ring-of-3
    (void)hipFuncSetAttribute((const void*)gemm_qkv_k,
                              hipFuncAttributeMaxDynamicSharedMemorySize, LDS_QKV);
    (void)hipFuncSetAttribute((const void*)gemm_o_k,
                              hipFuncAttributeMaxDynamicSharedMemorySize, LDS_O);

    cast_bf16_k<<<8192, 256, 0, stream>>>(x, x_bf, 2097152);
    transpose_cast_k<<<dim3(64, 64), dim3(32, 8), 0, stream>>>(Wq, Wqkv_t, 2048, 2048);
    transpose_cast_k<<<dim3(16, 64), dim3(32, 8), 0, stream>>>(Wk, Wqkv_t + (size_t)2048 * 2048, 2048, 512);
    transpose_cast_k<<<dim3(16, 64), dim3(32, 8), 0, stream>>>(Wv, Wqkv_t + (size_t)2560 * 2048, 2048, 512);
    transpose_cast_k<<<dim3(64, 64), dim3(32, 8), 0, stream>>>(Wo, Wo_t, 2048, 2048);

    // merged QKV projection: 256x256 BK=32 ring-3 counted-vmcnt, grid (16,12)=192
    gemm_qkv_k<<<dim3(16, 12), 512, LDS_QKV, stream>>>(x_bf, Wqkv_t, Qp, Kp, Vtb,
                                                       rc, rs, 4096, 3072, 2048);

    attn_k<<<dim3(16, 32, 2), 256, 0, stream>>>(Qp, Kp, Vtb, Ab);

    // O projection: grid (32,8)=256 blocks (full GPU), ring-3 counted vmcnt
    gemm_o_k<<<dim3(32, 8), 512, LDS_O, stream>>>(Ab, Wo_t, out, 4096, 2048, 2048);
}

// Round 16
// 169.503 us; speedup vs baseline: 1.0855x; 1.0855x over previous
//
#include <hip/hip_runtime.h>
#include <hip/hip_bf16.h>

typedef __attribute__((ext_vector_type(8))) short short8;
typedef __attribute__((ext_vector_type(4))) short short4v;
typedef __attribute__((ext_vector_type(4))) float f32x4;

#define MFMA(A,B,C) __builtin_amdgcn_mfma_f32_16x16x32_bf16(A,B,C,0,0,0)
// swizzle: 3 bits from row bits {0,1,3} so fragment reads spread 8 bank-quads
#define SW(row) ((((row) & 3)) | (((row) >> 1) & 4))
#define SCL 0.18033688f  // 0.125 * log2(e): folded into Q so scores are base-2

__device__ __forceinline__ short f2bs(float f) {
    __hip_bfloat16 h = __float2bfloat16(f);
    union { __hip_bfloat16 h; short s; } u; u.h = h; return u.s;
}

__device__ __forceinline__ float exp2v(float x) {  // bare v_exp_f32 (D = 2^S0)
    float r; asm("v_exp_f32 %0, %1" : "=v"(r) : "v"(x)); return r;
}

__device__ __forceinline__ unsigned cvtpk(float a, float b) {  // bf16(a) | bf16(b)<<16
    unsigned r; asm("v_cvt_pk_bf16_f32 %0, %1, %2" : "=v"(r) : "v"(a), "v"(b)); return r;
}

__device__ __forceinline__ void async16(void* lds, const void* g) {
    __builtin_amdgcn_global_load_lds(
        (const __attribute__((address_space(1))) unsigned int*)g,
        (__attribute__((address_space(3))) unsigned int*)lds, 16, 0, 0);
}

// ---------------- fused pre-pass: x cast + all 4 weight transposes ----------------
// blocks [0,8192): x fp32 -> bf16, 1024 elems/block.
// blocks [8192,..): 32x32 transpose+cast tiles:
//   Wq -> Wqkv_t[0..2048)        (4096 blocks, nbx=64)
//   Wk -> Wqkv_t[2048..2560)     (1024 blocks, nbx=16)
//   Wv -> Wqkv_t[2560..3072)     (1024 blocks, nbx=16)
//   Wo -> Wo_t                   (4096 blocks, nbx=64)
__global__ __launch_bounds__(256) void prep_k(
    const float* __restrict__ x,
    const float* __restrict__ Wq, const float* __restrict__ Wk,
    const float* __restrict__ Wv, const float* __restrict__ Wo,
    short* __restrict__ x_bf, short* __restrict__ Wqkv_t, short* __restrict__ Wo_t)
{
    __shared__ float tile[32][33];
    int bid = blockIdx.x;
    const int t = threadIdx.x;

    if (bid < 8192) {           // ---- cast x ----
        int i = bid * 256 + t;
        const float4 v = *(const float4*)(x + (size_t)i * 4);
        short4v o;
        o.x = f2bs(v.x); o.y = f2bs(v.y); o.z = f2bs(v.z); o.w = f2bs(v.w);
        *(short4v*)(x_bf + (size_t)i * 4) = o;
        return;
    }
    bid -= 8192;

    const float* W; short* Wt; int nbx;
    const int K = 2048;
    if (bid < 4096)      { W = Wq; Wt = Wqkv_t;                          nbx = 64; }
    else if (bid < 5120) { bid -= 4096; W = Wk; Wt = Wqkv_t + (size_t)2048 * 2048; nbx = 16; }
    else if (bid < 6144) { bid -= 5120; W = Wv; Wt = Wqkv_t + (size_t)2560 * 2048; nbx = 16; }
    else                 { bid -= 6144; W = Wo; Wt = Wo_t;               nbx = 64; }
    const int N = nbx * 32;
    const int tx = t & 31, ty = t >> 5;
    const int n0 = (bid % nbx) * 32, k0 = (bid / nbx) * 32;

    #pragma unroll
    for (int i = 0; i < 32; i += 8)
        tile[ty + i][tx] = W[(size_t)(k0 + ty + i) * N + n0 + tx];
    __syncthreads();
    #pragma unroll
    for (int i = 0; i < 32; i += 8)
        Wt[(size_t)(n0 + ty + i) * K + k0 + tx] = f2bs(tile[tx][ty + i]);
}

// ---------------- QKV GEMM: 256x256, 4 phases x 16 MFMA, dbuf (r11 proven) ----------------
// cols [0,2048) Q rope*SCL pack; [2048,2560) K rope pack; [2560,3072) V transposed
__global__ __launch_bounds__(512, 2) void gemm_qkv_k(
    const short* __restrict__ A, const short* __restrict__ Bt,
    short* __restrict__ Cq, short* __restrict__ Ck, short* __restrict__ Cv,
    const float* __restrict__ rc, const float* __restrict__ rs,
    int M, int N, int K)
{
    extern __shared__ short lds[];   // 2 bufs x (A 256x64 | B 256x64) = 2 x 32768 shorts
    const int t = threadIdx.x;
    const int l = t & 63, w = t >> 6;
    const int lo = l & 15, hi = l >> 4;
    const int wm = w >> 2, wn = w & 3;       // 2M x 4N
    const int lr = l >> 3, ls = l & 7;

    const int nbx = gridDim.x;
    const int nwg = nbx * gridDim.y;
    const int bid0 = blockIdx.y * nbx + blockIdx.x;
    const int wg = (bid0 & 7) * (nwg >> 3) + (bid0 >> 3);
    const int tm = (wg % nbx) * 256, tn = (wg / nbx) * 256;

    const f32x4 z4 = {0.f, 0.f, 0.f, 0.f};
    f32x4 acc[8][4];
    #pragma unroll
    for (int m = 0; m < 8; ++m)
        #pragma unroll
        for (int n = 0; n < 4; ++n) acc[m][n] = z4;

    auto stage_half = [&](int kt, int buf, int h) {
        const size_t ko = (size_t)kt * 64;
        const short* src = (h < 2) ? A : Bt;
        const int rbase = (h == 1 || h == 3) ? 128 : 0;
        const int gbase = (h < 2) ? tm : tn;
        short* dst = lds + buf * 32768 + ((h < 2) ? 0 : 16384) + rbase * 64;
        #pragma unroll
        for (int j = 0; j < 2; ++j) {
            int g = w * 2 + j;
            int row = g * 8 + lr;
            int gs = ls ^ SW(row);
            async16(dst + g * 512, src + (size_t)(gbase + rbase + row) * K + ko + gs * 8);
        }
    };

    const int nkt = K >> 6;
    #pragma unroll
    for (int h = 0; h < 4; ++h) stage_half(0, 0, h);
    __syncthreads();

    int cur = 0;
    for (int kt = 0; kt < nkt; ++kt) {
        const bool pf = (kt + 1 < nkt);
        const short* Ab_ = lds + cur * 32768;
        const short* Bb_ = Ab_ + 16384;
        short8 af[4], bfr[4];
        #pragma unroll
        for (int ph = 0; ph < 4; ++ph) {      // ph = ks*2 + mhalf
            const int ks = ph >> 1, mh = ph & 1;
            const int slot = ks * 4 + hi;
            #pragma unroll
            for (int mm = 0; mm < 4; ++mm) {
                int row = wm * 128 + (mh * 4 + mm) * 16 + lo;
                af[mm] = *(const short8*)(Ab_ + row * 64 + ((slot ^ SW(row)) << 3));
            }
            if (mh == 0) {
                #pragma unroll
                for (int n = 0; n < 4; ++n) {
                    int row = wn * 64 + n * 16 + lo;
                    bfr[n] = *(const short8*)(Bb_ + row * 64 + ((slot ^ SW(row)) << 3));
                }
            }
            if (pf && ph < 2) {
                stage_half(kt + 1, cur ^ 1, ph * 2);
                stage_half(kt + 1, cur ^ 1, ph * 2 + 1);
            }
            __builtin_amdgcn_s_barrier();
            asm volatile("s_waitcnt lgkmcnt(0)" ::: "memory");
            __builtin_amdgcn_sched_barrier(0);
            __builtin_amdgcn_s_setprio(1);
            #pragma unroll
            for (int n = 0; n < 4; ++n)
                #pragma unroll
                for (int mm = 0; mm < 4; ++mm)
                    acc[mh * 4 + mm][n] = MFMA(af[mm], bfr[n], acc[mh * 4 + mm][n]);
            __builtin_amdgcn_s_setprio(0);
            if (ph == 3 && pf)
                asm volatile("s_waitcnt vmcnt(0)" ::: "memory");
            __builtin_amdgcn_s_barrier();
        }
        cur ^= 1;
    }

    const int ctn = tn + wn * 64;
    if (ctn < 2048) {              // ---- Q: rope + fold softmax scale ----
        #pragma unroll
        for (int m = 0; m < 8; ++m)
            #pragma unroll
            for (int r = 0; r < 4; ++r) {
                int row = tm + wm * 128 + m * 16 + hi * 4 + r;
                int b = row >> 11, s = row & 2047;
                #pragma unroll
                for (int n = 0; n < 2; ++n) {
                    int col = ctn + n * 16 + lo;
                    int h = col >> 6, d = col & 63;  // d < 32
                    float x1 = acc[m][n][r], x2 = acc[m][n + 2][r];
                    float c = rc[s * 32 + d], sn = rs[s * 32 + d];
                    size_t base = (((size_t)b * 32 + h) * 2048 + s) * 64;
                    Cq[base + d]      = f2bs((x1 * c - x2 * sn) * SCL);
                    Cq[base + d + 32] = f2bs((x1 * sn + x2 * c) * SCL);
                }
            }
    } else if (ctn < 2560) {       // ---- K: rope pack ----
        #pragma unroll
        for (int m = 0; m < 8; ++m)
            #pragma unroll
            for (int r = 0; r < 4; ++r) {
                int row = tm + wm * 128 + m * 16 + hi * 4 + r;
                int b = row >> 11, s = row & 2047;
                #pragma unroll
                for (int n = 0; n < 2; ++n) {
                    int col = ctn - 2048 + n * 16 + lo;
                    int h = col >> 6, d = col & 63;  // d < 32
                    float x1 = acc[m][n][r], x2 = acc[m][n + 2][r];
                    float c = rc[s * 32 + d], sn = rs[s * 32 + d];
                    size_t base = (((size_t)b * 8 + h) * 2048 + s) * 64;
                    Ck[base + d]      = f2bs(x1 * c - x2 * sn);
                    Ck[base + d + 32] = f2bs(x1 * sn + x2 * c);
                }
            }
    } else {                       // ---- V: transposed pack (b,8,64,2048) ----
        #pragma unroll
        for (int m = 0; m < 8; ++m)
            #pragma unroll
            for (int r = 0; r < 4; ++r) {
                int row = tm + wm * 128 + m * 16 + hi * 4 + r;
                int b = row >> 11, s = row & 2047;
                #pragma unroll
                for (int n = 0; n < 4; ++n) {
                    int col = ctn - 2560 + n * 16 + lo;
                    int h = col >> 6, d = col & 63;
                    Cv[(((size_t)b * 8 + h) * 64 + d) * 2048 + s] = f2bs(acc[m][n][r]);
                }
            }
    }
}

// ---------------- O-proj GEMM: 128x256 tile, BK=64, ring-of-3, counted vmcnt ----------------
__global__ __launch_bounds__(512, 2) void gemm_o_k(
    const short* __restrict__ A, const short* __restrict__ Bt,
    float* __restrict__ Cf, int M, int N, int K)
{
    extern __shared__ short lds[];   // 3 bufs x (A 128x64 | B 256x64) = 3 x 24576 shorts
    const int t = threadIdx.x;
    const int l = t & 63, w = t >> 6;
    const int lo = l & 15, hi = l >> 4;
    const int wm = w >> 2, wn = w & 3;     // 2M x 4N
    const int lr = l >> 3, ls = l & 7;

    const int nbx = gridDim.x;             // 32
    const int nwg = nbx * gridDim.y;       // 256
    const int bid0 = blockIdx.y * nbx + blockIdx.x;
    const int wg = (bid0 & 7) * (nwg >> 3) + (bid0 >> 3);
    const int tm = (wg % nbx) * 128, tn = (wg / nbx) * 256;

    const f32x4 z4 = {0.f, 0.f, 0.f, 0.f};
    f32x4 acc[4][4];
    #pragma unroll
    for (int m = 0; m < 4; ++m)
        #pragma unroll
        for (int n = 0; n < 4; ++n) acc[m][n] = z4;

    const int srow = w * 8 + lr;
    const int sswz = ls ^ SW(srow);

    auto stage_unit = [&](int kt, int buf, int u) {
        const size_t ko = (size_t)kt * 64;
        short* base = lds + buf * 24576;
        if (u < 2)
            async16(base + u * 4096 + w * 512,
                    A + (size_t)(tm + u * 64 + srow) * K + ko + sswz * 8);
        else
            async16(base + 8192 + (u - 2) * 4096 + w * 512,
                    Bt + (size_t)(tn + (u - 2) * 64 + srow) * K + ko + sswz * 8);
    };

    const int nkt = K >> 6;   // 32
    #pragma unroll
    for (int u = 0; u < 6; ++u) stage_unit(0, 0, u);
    #pragma unroll
    for (int u = 0; u < 6; ++u) stage_unit(1, 1, u);
    asm volatile("s_waitcnt vmcnt(6)" ::: "memory");
    __builtin_amdgcn_s_barrier();

    int cur = 0;
    for (int kt = 0; kt < nkt; ++kt) {
        int tgt = cur + 2; if (tgt >= 3) tgt -= 3;
        const bool pf2 = (kt + 2 < nkt);
        const bool pf1 = (kt + 1 < nkt);
        const short* Ab_ = lds + cur * 24576;
        const short* Bb_ = Ab_ + 8192;
        short8 af[4], bfr[4];
        #pragma unroll
        for (int ph = 0; ph < 2; ++ph) {
            const int slot = ph * 4 + hi;
            #pragma unroll
            for (int mm = 0; mm < 4; ++mm) {
                int row = wm * 64 + mm * 16 + lo;
                af[mm] = *(const short8*)(Ab_ + row * 64 + ((slot ^ SW(row)) << 3));
            }
            #pragma unroll
            for (int n = 0; n < 4; ++n) {
                int row = wn * 64 + n * 16 + lo;
                bfr[n] = *(const short8*)(Bb_ + row * 64 + ((slot ^ SW(row)) << 3));
            }
            if (pf2) {
                stage_unit(kt + 2, tgt, ph * 3);
                stage_unit(kt + 2, tgt, ph * 3 + 1);
                stage_unit(kt + 2, tgt, ph * 3 + 2);
            }
            __builtin_amdgcn_s_barrier();
            asm volatile("s_waitcnt lgkmcnt(0)" ::: "memory");
            __builtin_amdgcn_sched_barrier(0);
            __builtin_amdgcn_s_setprio(1);
            #pragma unroll
            for (int n = 0; n < 4; ++n)
                #pragma unroll
                for (int mm = 0; mm < 4; ++mm)
                    acc[mm][n] = MFMA(af[mm], bfr[n], acc[mm][n]);
            __builtin_amdgcn_s_setprio(0);
            if (ph == 1) {
                if (pf2)      asm volatile("s_waitcnt vmcnt(6)" ::: "memory");
                else if (pf1) asm volatile("s_waitcnt vmcnt(0)" ::: "memory");
            }
            __builtin_amdgcn_s_barrier();
        }
        cur = (cur == 2) ? 0 : cur + 1;
    }

    #pragma unroll
    for (int m = 0; m < 4; ++m)
        #pragma unroll
        for (int r = 0; r < 4; ++r) {
            int row = tm + wm * 64 + m * 16 + hi * 4 + r;
            #pragma unroll
            for (int n = 0; n < 4; ++n) {
                int col = tn + wn * 64 + n * 16 + lo;
                Cf[(size_t)row * N + col] = acc[m][n][r];
            }
        }
}

// ---------------- flash attention, pair-balanced, no-max softmax ----------------
__global__ __launch_bounds__(256) void attn_k(
    const short* __restrict__ Qp, const short* __restrict__ Kp, const short* __restrict__ Vt,
    short* __restrict__ Ab)
{
    __shared__ short KV[2][8192];  // [buf][ K:0..4095 | V:4096..8191 ], 32 KB
    const int t = threadIdx.x, l = t & 63, w = t >> 6;
    const int lo = l & 15, hi = l >> 4;
    const int lr = l >> 3, ls = l & 7;
    const int pair = blockIdx.x;   // 0..15
    const int h = blockIdx.y, b = blockIdx.z;
    const int kvh = h >> 2;
    const size_t qbase  = (size_t)(b * 32 + h) * 2048 * 64;
    const size_t kbase  = (size_t)(b * 8 + kvh) * 2048 * 64;
    const size_t vtbase = (size_t)(b * 8 + kvh) * 64 * 2048;
    const size_t abase  = (size_t)b * 2048 * 2048 + (size_t)h * 64;

    for (int halfq = 0; halfq < 2; ++halfq) {
        const int qtile = halfq ? 31 - pair : pair;
        const int nkt = qtile + 1;

        short8 qf[2];
        {
            int qrow = qtile * 64 + w * 16 + lo;
            #pragma unroll
            for (int ks = 0; ks < 2; ++ks)
                qf[ks] = *(const short8*)(Qp + qbase + (size_t)qrow * 64 + (ks * 4 + hi) * 8);
        }

        const f32x4 z4 = {0.f, 0.f, 0.f, 0.f};
        float l_run = 0.f;
        f32x4 oacc[4];
        #pragma unroll
        for (int nd = 0; nd < 4; ++nd) oacc[nd] = z4;

        #pragma unroll
        for (int j = 0; j < 2; ++j) {
            int g8 = w * 2 + j;
            int row = g8 * 8 + lr;
            int gs = ls ^ SW(row);
            async16(&KV[0][g8 * 512],        Kp + kbase + (size_t)row * 64 + gs * 8);
            async16(&KV[0][4096 + g8 * 512], Vt + vtbase + (size_t)row * 2048 + gs * 8);
        }
        __syncthreads();

        int cur = 0;
        for (int kt = 0; kt < nkt; ++kt) {
            if (kt + 1 < nkt) {
                #pragma unroll
                for (int j = 0; j < 2; ++j) {
                    int g8 = w * 2 + j;
                    int row = g8 * 8 + lr;
                    int gs = ls ^ SW(row);
                    async16(&KV[cur ^ 1][g8 * 512],
                            Kp + kbase + (size_t)((kt + 1) * 64 + row) * 64 + gs * 8);
                    async16(&KV[cur ^ 1][4096 + g8 * 512],
                            Vt + vtbase + (size_t)row * 2048 + (kt + 1) * 64 + gs * 8);
                }
            }

            const short* Ks = &KV[cur][0];
            const short* Vs = &KV[cur][4096];

            f32x4 sacc[4];
            #pragma unroll
            for (int n = 0; n < 4; ++n) sacc[n] = z4;
            __builtin_amdgcn_s_setprio(1);
            #pragma unroll
            for (int ks = 0; ks < 2; ++ks) {
                const int slot = ks * 4 + hi;
                #pragma unroll
                for (int n = 0; n < 4; ++n) {
                    const int krow = ((lo >> 2) << 3) + ((n & 1) << 2) + (lo & 3) + ((n >> 1) << 5);
                    short8 kf = *(const short8*)(Ks + krow * 64 + ((slot ^ SW(krow)) << 3));
                    sacc[n] = MFMA(kf, qf[ks], sacc[n]);
                }
            }
            __builtin_amdgcn_s_setprio(0);

            float p[4][4];
            if (kt == qtile) {
                const int q = qtile * 64 + w * 16 + lo;
                #pragma unroll
                for (int n = 0; n < 4; ++n)
                    #pragma unroll
                    for (int r = 0; r < 4; ++r) {
                        int k = kt * 64 + hi * 8 + ((n & 1) << 2) + r + ((n >> 1) << 5);
                        p[n][r] = exp2v((k > q) ? -3e38f : sacc[n][r]);
                    }
            } else {
                #pragma unroll
                for (int n = 0; n < 4; ++n)
                    #pragma unroll
                    for (int r = 0; r < 4; ++r)
                        p[n][r] = exp2v(sacc[n][r]);
            }
            float rs0 = 0.f, rs1 = 0.f;
            #pragma unroll
            for (int n = 0; n < 4; ++n) {
                rs0 += p[n][0] + p[n][1];
                rs1 += p[n][2] + p[n][3];
            }
            l_run += rs0 + rs1;

            short8 afr[2];
            #pragma unroll
            for (int ks = 0; ks < 2; ++ks) {
                union { short8 s; unsigned u[4]; } pk;
                pk.u[0] = cvtpk(p[2 * ks][0],     p[2 * ks][1]);
                pk.u[1] = cvtpk(p[2 * ks][2],     p[2 * ks][3]);
                pk.u[2] = cvtpk(p[2 * ks + 1][0], p[2 * ks + 1][1]);
                pk.u[3] = cvtpk(p[2 * ks + 1][2], p[2 * ks + 1][3]);
                afr[ks] = pk.s;
            }

            __builtin_amdgcn_s_setprio(1);
            #pragma unroll
            for (int ks = 0; ks < 2; ++ks) {
                const int slot = ks * 4 + hi;
                #pragma unroll
                for (int nd = 0; nd < 4; ++nd) {
                    const int vrow = nd * 16 + lo;
                    short8 vf = *(const short8*)(Vs + vrow * 64 + ((slot ^ SW(vrow)) << 3));
                    oacc[nd] = MFMA(afr[ks], vf, oacc[nd]);
                }
            }
            __builtin_amdgcn_s_setprio(0);

            __syncthreads();
            cur ^= 1;
        }

        l_run += __shfl_xor(l_run, 16, 64);
        l_run += __shfl_xor(l_run, 32, 64);
        float rl[4];
        #pragma unroll
        for (int r = 0; r < 4; ++r)
            rl[r] = 1.0f / __shfl(l_run, (l & 48) | (hi * 4 + r), 64);
        #pragma unroll
        for (int nd = 0; nd < 4; ++nd)
            #pragma unroll
            for (int r = 0; r < 4; ++r) {
                int s = qtile * 64 + w * 16 + hi * 4 + r;
                Ab[abase + (size_t)s * 2048 + nd * 16 + lo] = f2bs(oacc[nd][r] * rl[r]);
            }
    }
}

extern "C" void kernel_launch(void* const* d_in, const int* in_sizes, int n_in,
                              void* d_out, int out_size, void* d_ws, size_t ws_size,
                              hipStream_t stream)
{
    const float* x  = (const float*)d_in[0];
    const float* Wq = (const float*)d_in[1];
    const float* Wk = (const float*)d_in[2];
    const float* Wv = (const float*)d_in[3];
    const float* Wo = (const float*)d_in[4];
    const float* rc = (const float*)d_in[5];
    const float* rs = (const float*)d_in[6];
    float* out = (float*)d_out;
    char* ws = (char*)d_ws;

    size_t off = 0;
    short* x_bf   = (short*)(ws + off); off += (size_t)4096 * 2048 * 2;
    short* Wqkv_t = (short*)(ws + off); off += (size_t)3072 * 2048 * 2;
    short* Wo_t   = (short*)(ws + off); off += (size_t)2048 * 2048 * 2;
    short* Qp     = (short*)(ws + off); off += (size_t)2 * 32 * 2048 * 64 * 2;
    short* Kp     = (short*)(ws + off); off += (size_t)2 * 8 * 2048 * 64 * 2;
    short* Vtb    = (short*)(ws + off); off += (size_t)2 * 8 * 64 * 2048 * 2;
    short* Ab     = (short*)(ws + off); off += (size_t)4096 * 2048 * 2;
    if (off > ws_size) return;

    const int LDS_QKV = 2 * 32768 * 2;   // 128 KB double buffer
    const int LDS_O   = 3 * 24576 * 2;   // 144 KB ring-of-3
    (void)hipFuncSetAttribute((const void*)gemm_qkv_k,
                              hipFuncAttributeMaxDynamicSharedMemorySize, LDS_QKV);
    (void)hipFuncSetAttribute((const void*)gemm_o_k,
                              hipFuncAttributeMaxDynamicSharedMemorySize, LDS_O);

    // fused pre-pass: cast (8192) + Wq (4096) + Wk (1024) + Wv (1024) + Wo (4096)
    prep_k<<<18432, 256, 0, stream>>>(x, Wq, Wk, Wv, Wo, x_bf, Wqkv_t, Wo_t);

    // merged QKV projection: 256x256 4-phase dbuf (r11), grid (16,12)=192
    gemm_qkv_k<<<dim3(16, 12), 512, LDS_QKV, stream>>>(x_bf, Wqkv_t, Qp, Kp, Vtb,
                                                       rc, rs, 4096, 3072, 2048);

    attn_k<<<dim3(16, 32, 2), 256, 0, stream>>>(Qp, Kp, Vtb, Ab);

    // O projection: grid (32,8)=256 blocks (full GPU), ring-3 counted vmcnt
    gemm_o_k<<<dim3(32, 8), 512, LDS_O, stream>>>(Ab, Wo_t, out, 4096, 2048, 2048);
}

// Round 17
// 169.360 us; speedup vs baseline: 1.0864x; 1.0008x over previous
//
#include <hip/hip_runtime.h>
#include <hip/hip_bf16.h>

typedef __attribute__((ext_vector_type(8))) short short8;
typedef __attribute__((ext_vector_type(4))) short short4v;
typedef __attribute__((ext_vector_type(4))) float f32x4;

#define MFMA(A,B,C) __builtin_amdgcn_mfma_f32_16x16x32_bf16(A,B,C,0,0,0)
// swizzle: 3 bits from row bits {0,1,3} so fragment reads spread 8 bank-quads
#define SW(row) ((((row) & 3)) | (((row) >> 1) & 4))
#define SCL 0.18033688f  // 0.125 * log2(e): folded into Q so scores are base-2

__device__ __forceinline__ short f2bs(float f) {
    __hip_bfloat16 h = __float2bfloat16(f);
    union { __hip_bfloat16 h; short s; } u; u.h = h; return u.s;
}

__device__ __forceinline__ float exp2v(float x) {  // bare v_exp_f32 (D = 2^S0)
    float r; asm("v_exp_f32 %0, %1" : "=v"(r) : "v"(x)); return r;
}

__device__ __forceinline__ unsigned cvtpk(float a, float b) {  // bf16(a) | bf16(b)<<16
    unsigned r; asm("v_cvt_pk_bf16_f32 %0, %1, %2" : "=v"(r) : "v"(a), "v"(b)); return r;
}

__device__ __forceinline__ void async16(void* lds, const void* g) {
    __builtin_amdgcn_global_load_lds(
        (const __attribute__((address_space(1))) unsigned int*)g,
        (__attribute__((address_space(3))) unsigned int*)lds, 16, 0, 0);
}

// ---------------- fused pre-pass: x cast + all 4 weight transposes ----------------
__global__ __launch_bounds__(256) void prep_k(
    const float* __restrict__ x,
    const float* __restrict__ Wq, const float* __restrict__ Wk,
    const float* __restrict__ Wv, const float* __restrict__ Wo,
    short* __restrict__ x_bf, short* __restrict__ Wqkv_t, short* __restrict__ Wo_t)
{
    __shared__ float tile[32][33];
    int bid = blockIdx.x;
    const int t = threadIdx.x;

    if (bid < 8192) {           // ---- cast x ----
        int i = bid * 256 + t;
        const float4 v = *(const float4*)(x + (size_t)i * 4);
        short4v o;
        o.x = f2bs(v.x); o.y = f2bs(v.y); o.z = f2bs(v.z); o.w = f2bs(v.w);
        *(short4v*)(x_bf + (size_t)i * 4) = o;
        return;
    }
    bid -= 8192;

    const float* W; short* Wt; int nbx;
    const int K = 2048;
    if (bid < 4096)      { W = Wq; Wt = Wqkv_t;                          nbx = 64; }
    else if (bid < 5120) { bid -= 4096; W = Wk; Wt = Wqkv_t + (size_t)2048 * 2048; nbx = 16; }
    else if (bid < 6144) { bid -= 5120; W = Wv; Wt = Wqkv_t + (size_t)2560 * 2048; nbx = 16; }
    else                 { bid -= 6144; W = Wo; Wt = Wo_t;               nbx = 64; }
    const int N = nbx * 32;
    const int tx = t & 31, ty = t >> 5;
    const int n0 = (bid % nbx) * 32, k0 = (bid / nbx) * 32;

    #pragma unroll
    for (int i = 0; i < 32; i += 8)
        tile[ty + i][tx] = W[(size_t)(k0 + ty + i) * N + n0 + tx];
    __syncthreads();
    #pragma unroll
    for (int i = 0; i < 32; i += 8)
        Wt[(size_t)(n0 + ty + i) * K + k0 + tx] = f2bs(tile[tx][ty + i]);
}

// ---------------- QKV GEMM: 256x256 dbuf, single-region K-tiles ----------------
// 8 waves (2Mx4N), wave 128x64, 64 MFMA per K-tile in ONE compute region (no
// internal barriers/lgkmcnt pins: compiler schedules fine-grained lgkm waits and
// interleaves ds_read with MFMA). All 8 stage loads of tile kt+1 issued at tile-kt
// start (full-tile latency cover). Per-wave counted vmcnt at the boundary: wave
// (wm,wn) waits only for its own operand units. Stage order: A0(2) B0(1) A1(2)
// B1(1) B2(1) B3(1) -> vmcnt by wave = {5,2,1,0,3,2,1,0}. One barrier per K-tile.
// Epilogue: cols [0,2048) Q rope*SCL; [2048,2560) K rope; [2560,3072) V transpose.
__global__ __launch_bounds__(512, 2) void gemm_qkv_k(
    const short* __restrict__ A, const short* __restrict__ Bt,
    short* __restrict__ Cq, short* __restrict__ Ck, short* __restrict__ Cv,
    const float* __restrict__ rc, const float* __restrict__ rs,
    int M, int N, int K)
{
    extern __shared__ short lds[];   // 2 bufs x (A 256x64 | B 256x64) = 2 x 32768 shorts
    const int t = threadIdx.x;
    const int l = t & 63, w = t >> 6;
    const int lo = l & 15, hi = l >> 4;
    const int wm = w >> 2, wn = w & 3;       // 2M x 4N
    const int lr8 = l >> 3, ls8 = l & 7;

    const int nbx = gridDim.x;
    const int nwg = nbx * gridDim.y;
    const int bid0 = blockIdx.y * nbx + blockIdx.x;
    const int wg = (bid0 & 7) * (nwg >> 3) + (bid0 >> 3);
    const int tm = (wg % nbx) * 256, tn = (wg / nbx) * 256;

    const f32x4 z4 = {0.f, 0.f, 0.f, 0.f};
    f32x4 acc[8][4];
    #pragma unroll
    for (int m = 0; m < 8; ++m)
        #pragma unroll
        for (int n = 0; n < 4; ++n) acc[m][n] = z4;

    // A half h (128 rows): 2 loads/thread. rows g*8+lr8, g = w*2+j (16 groups).
    auto stageA = [&](int kt, int buf, int h) {
        const size_t ko = (size_t)kt * 64;
        const int rbase = h * 128;
        short* dst = lds + buf * 32768 + rbase * 64;
        #pragma unroll
        for (int j = 0; j < 2; ++j) {
            int g = w * 2 + j;
            int row = g * 8 + lr8;            // local row; SW unaffected by +128
            int gs = ls8 ^ SW(row);
            async16(dst + g * 512, A + (size_t)(tm + rbase + row) * K + ko + gs * 8);
        }
    };
    // B unit j (64 rows = wn strip j): 1 load/thread. wave w covers rows j*64+w*8..+7.
    auto stageB = [&](int kt, int buf, int j) {
        const size_t ko = (size_t)kt * 64;
        short* dst = lds + buf * 32768 + 16384 + j * 4096 + w * 512;
        int row = j * 64 + w * 8 + lr8;
        int gs = ls8 ^ SW(row);
        async16(dst, Bt + (size_t)(tn + row) * K + ko + gs * 8);
    };
    auto stage_tile = [&](int kt, int buf) {   // issue order fixes vmcnt ledger
        stageA(kt, buf, 0);   // loads 1-2
        stageB(kt, buf, 0);   // load  3
        stageA(kt, buf, 1);   // loads 4-5
        stageB(kt, buf, 1);   // load  6
        stageB(kt, buf, 2);   // load  7
        stageB(kt, buf, 3);   // load  8
    };
    // per-wave wait: last-needed unit of wave (wm,wn); in-order retirement makes
    // these leftovers-safe.
    auto wave_wait = [&]() {
        switch (w) {
            case 0: asm volatile("s_waitcnt vmcnt(5)" ::: "memory"); break;
            case 1: asm volatile("s_waitcnt vmcnt(2)" ::: "memory"); break;
            case 2: asm volatile("s_waitcnt vmcnt(1)" ::: "memory"); break;
            case 3: asm volatile("s_waitcnt vmcnt(0)" ::: "memory"); break;
            case 4: asm volatile("s_waitcnt vmcnt(3)" ::: "memory"); break;
            case 5: asm volatile("s_waitcnt vmcnt(2)" ::: "memory"); break;
            case 6: asm volatile("s_waitcnt vmcnt(1)" ::: "memory"); break;
            default: asm volatile("s_waitcnt vmcnt(0)" ::: "memory"); break;
        }
    };

    const int nkt = K >> 6;   // 32
    stage_tile(0, 0);
    wave_wait();
    __builtin_amdgcn_s_barrier();

    int cur = 0;
    for (int kt = 0; kt < nkt; ++kt) {
        const bool pf = (kt + 1 < nkt);
        if (pf) stage_tile(kt + 1, cur ^ 1);
        const short* Ab_ = lds + cur * 32768;
        const short* Bb_ = Ab_ + 16384;

        __builtin_amdgcn_s_setprio(1);
        #pragma unroll
        for (int ks = 0; ks < 2; ++ks) {
            const int slot = ks * 4 + hi;
            short8 bfr[4];
            #pragma unroll
            for (int n = 0; n < 4; ++n) {
                int row = wn * 64 + n * 16 + lo;
                bfr[n] = *(const short8*)(Bb_ + row * 64 + ((slot ^ SW(row)) << 3));
            }
            #pragma unroll
            for (int mh = 0; mh < 2; ++mh) {
                short8 af[4];
                #pragma unroll
                for (int mm = 0; mm < 4; ++mm) {
                    int row = wm * 128 + (mh * 4 + mm) * 16 + lo;
                    af[mm] = *(const short8*)(Ab_ + row * 64 + ((slot ^ SW(row)) << 3));
                }
                #pragma unroll
                for (int n = 0; n < 4; ++n)
                    #pragma unroll
                    for (int mm = 0; mm < 4; ++mm)
                        acc[mh * 4 + mm][n] = MFMA(af[mm], bfr[n], acc[mh * 4 + mm][n]);
            }
        }
        __builtin_amdgcn_s_setprio(0);

        if (pf) {
            wave_wait();                       // next tile's own units landed
            __builtin_amdgcn_s_barrier();      // release cur for overwrite next tile
        }
        cur ^= 1;
    }

    const int ctn = tn + wn * 64;
    if (ctn < 2048) {              // ---- Q: rope + fold softmax scale ----
        #pragma unroll
        for (int m = 0; m < 8; ++m)
            #pragma unroll
            for (int r = 0; r < 4; ++r) {
                int row = tm + wm * 128 + m * 16 + hi * 4 + r;
                int b = row >> 11, s = row & 2047;
                #pragma unroll
                for (int n = 0; n < 2; ++n) {
                    int col = ctn + n * 16 + lo;
                    int h = col >> 6, d = col & 63;  // d < 32
                    float x1 = acc[m][n][r], x2 = acc[m][n + 2][r];
                    float c = rc[s * 32 + d], sn = rs[s * 32 + d];
                    size_t base = (((size_t)b * 32 + h) * 2048 + s) * 64;
                    Cq[base + d]      = f2bs((x1 * c - x2 * sn) * SCL);
                    Cq[base + d + 32] = f2bs((x1 * sn + x2 * c) * SCL);
                }
            }
    } else if (ctn < 2560) {       // ---- K: rope pack ----
        #pragma unroll
        for (int m = 0; m < 8; ++m)
            #pragma unroll
            for (int r = 0; r < 4; ++r) {
                int row = tm + wm * 128 + m * 16 + hi * 4 + r;
                int b = row >> 11, s = row & 2047;
                #pragma unroll
                for (int n = 0; n < 2; ++n) {
                    int col = ctn - 2048 + n * 16 + lo;
                    int h = col >> 6, d = col & 63;  // d < 32
                    float x1 = acc[m][n][r], x2 = acc[m][n + 2][r];
                    float c = rc[s * 32 + d], sn = rs[s * 32 + d];
                    size_t base = (((size_t)b * 8 + h) * 2048 + s) * 64;
                    Ck[base + d]      = f2bs(x1 * c - x2 * sn);
                    Ck[base + d + 32] = f2bs(x1 * sn + x2 * c);
                }
            }
    } else {                       // ---- V: transposed pack (b,8,64,2048) ----
        #pragma unroll
        for (int m = 0; m < 8; ++m)
            #pragma unroll
            for (int r = 0; r < 4; ++r) {
                int row = tm + wm * 128 + m * 16 + hi * 4 + r;
                int b = row >> 11, s = row & 2047;
                #pragma unroll
                for (int n = 0; n < 4; ++n) {
                    int col = ctn - 2560 + n * 16 + lo;
                    int h = col >> 6, d = col & 63;
                    Cv[(((size_t)b * 8 + h) * 64 + d) * 2048 + s] = f2bs(acc[m][n][r]);
                }
            }
    }
}

// ---------------- O-proj GEMM: 128x256 tile, BK=64, ring-of-3, counted vmcnt ----------------
__global__ __launch_bounds__(512, 2) void gemm_o_k(
    const short* __restrict__ A, const short* __restrict__ Bt,
    float* __restrict__ Cf, int M, int N, int K)
{
    extern __shared__ short lds[];   // 3 bufs x (A 128x64 | B 256x64) = 3 x 24576 shorts
    const int t = threadIdx.x;
    const int l = t & 63, w = t >> 6;
    const int lo = l & 15, hi = l >> 4;
    const int wm = w >> 2, wn = w & 3;     // 2M x 4N
    const int lr = l >> 3, ls = l & 7;

    const int nbx = gridDim.x;             // 32
    const int nwg = nbx * gridDim.y;       // 256
    const int bid0 = blockIdx.y * nbx + blockIdx.x;
    const int wg = (bid0 & 7) * (nwg >> 3) + (bid0 >> 3);
    const int tm = (wg % nbx) * 128, tn = (wg / nbx) * 256;

    const f32x4 z4 = {0.f, 0.f, 0.f, 0.f};
    f32x4 acc[4][4];
    #pragma unroll
    for (int m = 0; m < 4; ++m)
        #pragma unroll
        for (int n = 0; n < 4; ++n) acc[m][n] = z4;

    const int srow = w * 8 + lr;
    const int sswz = ls ^ SW(srow);

    auto stage_unit = [&](int kt, int buf, int u) {
        const size_t ko = (size_t)kt * 64;
        short* base = lds + buf * 24576;
        if (u < 2)
            async16(base + u * 4096 + w * 512,
                    A + (size_t)(tm + u * 64 + srow) * K + ko + sswz * 8);
        else
            async16(base + 8192 + (u - 2) * 4096 + w * 512,
                    Bt + (size_t)(tn + (u - 2) * 64 + srow) * K + ko + sswz * 8);
    };

    const int nkt = K >> 6;   // 32
    #pragma unroll
    for (int u = 0; u < 6; ++u) stage_unit(0, 0, u);
    #pragma unroll
    for (int u = 0; u < 6; ++u) stage_unit(1, 1, u);
    asm volatile("s_waitcnt vmcnt(6)" ::: "memory");
    __builtin_amdgcn_s_barrier();

    int cur = 0;
    for (int kt = 0; kt < nkt; ++kt) {
        int tgt = cur + 2; if (tgt >= 3) tgt -= 3;
        const bool pf2 = (kt + 2 < nkt);
        const bool pf1 = (kt + 1 < nkt);
        const short* Ab_ = lds + cur * 24576;
        const short* Bb_ = Ab_ + 8192;
        short8 af[4], bfr[4];
        #pragma unroll
        for (int ph = 0; ph < 2; ++ph) {
            const int slot = ph * 4 + hi;
            #pragma unroll
            for (int mm = 0; mm < 4; ++mm) {
                int row = wm * 64 + mm * 16 + lo;
                af[mm] = *(const short8*)(Ab_ + row * 64 + ((slot ^ SW(row)) << 3));
            }
            #pragma unroll
            for (int n = 0; n < 4; ++n) {
                int row = wn * 64 + n * 16 + lo;
                bfr[n] = *(const short8*)(Bb_ + row * 64 + ((slot ^ SW(row)) << 3));
            }
            if (pf2) {
                stage_unit(kt + 2, tgt, ph * 3);
                stage_unit(kt + 2, tgt, ph * 3 + 1);
                stage_unit(kt + 2, tgt, ph * 3 + 2);
            }
            __builtin_amdgcn_s_barrier();
            asm volatile("s_waitcnt lgkmcnt(0)" ::: "memory");
            __builtin_amdgcn_sched_barrier(0);
            __builtin_amdgcn_s_setprio(1);
            #pragma unroll
            for (int n = 0; n < 4; ++n)
                #pragma unroll
                for (int mm = 0; mm < 4; ++mm)
                    acc[mm][n] = MFMA(af[mm], bfr[n], acc[mm][n]);
            __builtin_amdgcn_s_setprio(0);
            if (ph == 1) {
                if (pf2)      asm volatile("s_waitcnt vmcnt(6)" ::: "memory");
                else if (pf1) asm volatile("s_waitcnt vmcnt(0)" ::: "memory");
            }
            __builtin_amdgcn_s_barrier();
        }
        cur = (cur == 2) ? 0 : cur + 1;
    }

    #pragma unroll
    for (int m = 0; m < 4; ++m)
        #pragma unroll
        for (int r = 0; r < 4; ++r) {
            int row = tm + wm * 64 + m * 16 + hi * 4 + r;
            #pragma unroll
            for (int n = 0; n < 4; ++n) {
                int col = tn + wn * 64 + n * 16 + lo;
                Cf[(size_t)row * N + col] = acc[m][n][r];
            }
        }
}

// ---------------- flash attention, pair-balanced, no-max softmax ----------------
__global__ __launch_bounds__(256) void attn_k(
    const short* __restrict__ Qp, const short* __restrict__ Kp, const short* __restrict__ Vt,
    short* __restrict__ Ab)
{
    __shared__ short KV[2][8192];  // [buf][ K:0..4095 | V:4096..8191 ], 32 KB
    const int t = threadIdx.x, l = t & 63, w = t >> 6;
    const int lo = l & 15, hi = l >> 4;
    const int lr = l >> 3, ls = l & 7;
    const int pair = blockIdx.x;   // 0..15
    const int h = blockIdx.y, b = blockIdx.z;
    const int kvh = h >> 2;
    const size_t qbase  = (size_t)(b * 32 + h) * 2048 * 64;
    const size_t kbase  = (size_t)(b * 8 + kvh) * 2048 * 64;
    const size_t vtbase = (size_t)(b * 8 + kvh) * 64 * 2048;
    const size_t abase  = (size_t)b * 2048 * 2048 + (size_t)h * 64;

    for (int halfq = 0; halfq < 2; ++halfq) {
        const int qtile = halfq ? 31 - pair : pair;
        const int nkt = qtile + 1;

        short8 qf[2];
        {
            int qrow = qtile * 64 + w * 16 + lo;
            #pragma unroll
            for (int ks = 0; ks < 2; ++ks)
                qf[ks] = *(const short8*)(Qp + qbase + (size_t)qrow * 64 + (ks * 4 + hi) * 8);
        }

        const f32x4 z4 = {0.f, 0.f, 0.f, 0.f};
        float l_run = 0.f;
        f32x4 oacc[4];
        #pragma unroll
        for (int nd = 0; nd < 4; ++nd) oacc[nd] = z4;

        #pragma unroll
        for (int j = 0; j < 2; ++j) {
            int g8 = w * 2 + j;
            int row = g8 * 8 + lr;
            int gs = ls ^ SW(row);
            async16(&KV[0][g8 * 512],        Kp + kbase + (size_t)row * 64 + gs * 8);
            async16(&KV[0][4096 + g8 * 512], Vt + vtbase + (size_t)row * 2048 + gs * 8);
        }
        __syncthreads();

        int cur = 0;
        for (int kt = 0; kt < nkt; ++kt) {
            if (kt + 1 < nkt) {
                #pragma unroll
                for (int j = 0; j < 2; ++j) {
                    int g8 = w * 2 + j;
                    int row = g8 * 8 + lr;
                    int gs = ls ^ SW(row);
                    async16(&KV[cur ^ 1][g8 * 512],
                            Kp + kbase + (size_t)((kt + 1) * 64 + row) * 64 + gs * 8);
                    async16(&KV[cur ^ 1][4096 + g8 * 512],
                            Vt + vtbase + (size_t)row * 2048 + (kt + 1) * 64 + gs * 8);
                }
            }

            const short* Ks = &KV[cur][0];
            const short* Vs = &KV[cur][4096];

            f32x4 sacc[4];
            #pragma unroll
            for (int n = 0; n < 4; ++n) sacc[n] = z4;
            __builtin_amdgcn_s_setprio(1);
            #pragma unroll
            for (int ks = 0; ks < 2; ++ks) {
                const int slot = ks * 4 + hi;
                #pragma unroll
                for (int n = 0; n < 4; ++n) {
                    const int krow = ((lo >> 2) << 3) + ((n & 1) << 2) + (lo & 3) + ((n >> 1) << 5);
                    short8 kf = *(const short8*)(Ks + krow * 64 + ((slot ^ SW(krow)) << 3));
                    sacc[n] = MFMA(kf, qf[ks], sacc[n]);
                }
            }
            __builtin_amdgcn_s_setprio(0);

            float p[4][4];
            if (kt == qtile) {
                const int q = qtile * 64 + w * 16 + lo;
                #pragma unroll
                for (int n = 0; n < 4; ++n)
                    #pragma unroll
                    for (int r = 0; r < 4; ++r) {
                        int k = kt * 64 + hi * 8 + ((n & 1) << 2) + r + ((n >> 1) << 5);
                        p[n][r] = exp2v((k > q) ? -3e38f : sacc[n][r]);
                    }
            } else {
                #pragma unroll
                for (int n = 0; n < 4; ++n)
                    #pragma unroll
                    for (int r = 0; r < 4; ++r)
                        p[n][r] = exp2v(sacc[n][r]);
            }
            float rs0 = 0.f, rs1 = 0.f;
            #pragma unroll
            for (int n = 0; n < 4; ++n) {
                rs0 += p[n][0] + p[n][1];
                rs1 += p[n][2] + p[n][3];
            }
            l_run += rs0 + rs1;

            short8 afr[2];
            #pragma unroll
            for (int ks = 0; ks < 2; ++ks) {
                union { short8 s; unsigned u[4]; } pk;
                pk.u[0] = cvtpk(p[2 * ks][0],     p[2 * ks][1]);
                pk.u[1] = cvtpk(p[2 * ks][2],     p[2 * ks][3]);
                pk.u[2] = cvtpk(p[2 * ks + 1][0], p[2 * ks + 1][1]);
                pk.u[3] = cvtpk(p[2 * ks + 1][2], p[2 * ks + 1][3]);
                afr[ks] = pk.s;
            }

            __builtin_amdgcn_s_setprio(1);
            #pragma unroll
            for (int ks = 0; ks < 2; ++ks) {
                const int slot = ks * 4 + hi;
                #pragma unroll
                for (int nd = 0; nd < 4; ++nd) {
                    const int vrow = nd * 16 + lo;
                    short8 vf = *(const short8*)(Vs + vrow * 64 + ((slot ^ SW(vrow)) << 3));
                    oacc[nd] = MFMA(afr[ks], vf, oacc[nd]);
                }
            }
            __builtin_amdgcn_s_setprio(0);

            __syncthreads();
            cur ^= 1;
        }

        l_run += __shfl_xor(l_run, 16, 64);
        l_run += __shfl_xor(l_run, 32, 64);
        float rl[4];
        #pragma unroll
        for (int r = 0; r < 4; ++r)
            rl[r] = 1.0f / __shfl(l_run, (l & 48) | (hi * 4 + r), 64);
        #pragma unroll
        for (int nd = 0; nd < 4; ++nd)
            #pragma unroll
            for (int r = 0; r < 4; ++r) {
                int s = qtile * 64 + w * 16 + hi * 4 + r;
                Ab[abase + (size_t)s * 2048 + nd * 16 + lo] = f2bs(oacc[nd][r] * rl[r]);
            }
    }
}

extern "C" void kernel_launch(void* const* d_in, const int* in_sizes, int n_in,
                              void* d_out, int out_size, void* d_ws, size_t ws_size,
                              hipStream_t stream)
{
    const float* x  = (const float*)d_in[0];
    const float* Wq = (const float*)d_in[1];
    const float* Wk = (const float*)d_in[2];
    const float* Wv = (const float*)d_in[3];
    const float* Wo = (const float*)d_in[4];
    const float* rc = (const float*)d_in[5];
    const float* rs = (const float*)d_in[6];
    float* out = (float*)d_out;
    char* ws = (char*)d_ws;

    size_t off = 0;
    short* x_bf   = (short*)(ws + off); off += (size_t)4096 * 2048 * 2;
    short* Wqkv_t = (short*)(ws + off); off += (size_t)3072 * 2048 * 2;
    short* Wo_t   = (short*)(ws + off); off += (size_t)2048 * 2048 * 2;
    short* Qp     = (short*)(ws + off); off += (size_t)2 * 32 * 2048 * 64 * 2;
    short* Kp     = (short*)(ws + off); off += (size_t)2 * 8 * 2048 * 64 * 2;
    short* Vtb    = (short*)(ws + off); off += (size_t)2 * 8 * 64 * 2048 * 2;
    short* Ab     = (short*)(ws + off); off += (size_t)4096 * 2048 * 2;
    if (off > ws_size) return;

    const int LDS_QKV = 2 * 32768 * 2;   // 128 KB double buffer
    const int LDS_O   = 3 * 24576 * 2;   // 144 KB ring-of-3
    (void)hipFuncSetAttribute((const void*)gemm_qkv_k,
                              hipFuncAttributeMaxDynamicSharedMemorySize, LDS_QKV);
    (void)hipFuncSetAttribute((const void*)gemm_o_k,
                              hipFuncAttributeMaxDynamicSharedMemorySize, LDS_O);

    // fused pre-pass: cast (8192) + Wq (4096) + Wk (1024) + Wv (1024) + Wo (4096)
    prep_k<<<18432, 256, 0, stream>>>(x, Wq, Wk, Wv, Wo, x_bf, Wqkv_t, Wo_t);

    // merged QKV projection: 256x256 dbuf single-region, grid (16,12)=192
    gemm_qkv_k<<<dim3(16, 12), 512, LDS_QKV, stream>>>(x_bf, Wqkv_t, Qp, Kp, Vtb,
                                                       rc, rs, 4096, 3072, 2048);

    attn_k<<<dim3(16, 32, 2), 256, 0, stream>>>(Qp, Kp, Vtb, Ab);

    // O projection: grid (32,8)=256 blocks (full GPU), ring-3 counted vmcnt
    gemm_o_k<<<dim3(32, 8), 512, LDS_O, stream>>>(Ab, Wo_t, out, 4096, 2048, 2048);
}